// Round 1
// baseline (422.191 us; speedup 1.0000x reference)
//
#include <hip/hip_runtime.h>
#include <hip/hip_bf16.h>

// Problem constants
#define B_ 4096
#define T_ 256
#define F_ 64
#define H_ 128
#define G_ 512   // 4*H
#define S_ 32

typedef __attribute__((ext_vector_type(8))) short bf16x8;
typedef __attribute__((ext_vector_type(4))) float f32x4;

// LDS row strides (in bf16 elements); multiples of 8 so 16B-aligned rows
#define XS 80    // x tile: 64 cols + 16 pad
#define HS 144   // h tile: 128 cols + 16 pad

__device__ __forceinline__ unsigned short f2bf(float f) {
    unsigned u = __builtin_bit_cast(unsigned, f);
    unsigned r = (u + 0x7FFFu + ((u >> 16) & 1u)) >> 16;   // round-nearest-even
    return (unsigned short)r;
}
__device__ __forceinline__ unsigned pack2(float lo, float hi) {
    return (unsigned)f2bf(lo) | ((unsigned)f2bf(hi) << 16);
}
__device__ __forceinline__ float sigmoidf_(float x) {
    return __fdividef(1.0f, 1.0f + __expf(-x));
}
__device__ __forceinline__ float tanhf_(float x) {
    return __fmaf_rn(2.0f, sigmoidf_(2.0f * x), -1.0f);
}

__global__ __launch_bounds__(512, 2) void lstm_fused_kernel(
    const float* __restrict__ x,      // [B,T,F]
    const float* __restrict__ statik, // [B,S]
    const float* __restrict__ hs0,    // [B,H]
    const float* __restrict__ cs0,    // [B,H]
    const float* __restrict__ W_ih,   // [G,F]
    const float* __restrict__ W_hh,   // [G,H]
    const float* __restrict__ b_ih,   // [G]
    const float* __restrict__ b_hh,   // [G]
    const float* __restrict__ W_lin,  // [H+S]
    const float* __restrict__ b_lin,  // [1]
    float* __restrict__ out)          // [B]
{
    __shared__ unsigned short x_lds[2][16 * XS];
    __shared__ unsigned short h_lds[2][16 * HS];
    __shared__ float h_f32[16][H_];

    const int tid  = threadIdx.x;
    const int lane = tid & 63;
    const int w    = tid >> 6;         // wave 0..7
    const int b0   = blockIdx.x * 16;  // first batch row of this block

    const int lrow = lane & 15;        // A-frag row / B-frag col / C col
    const int lkb  = lane >> 4;        // k-block 0..3 / C row-group

    // ---------- one-time: weight fragments into registers (bf16) ----------
    // gates[n] = sum_k in[k] * W[n][k], k<64 -> W_ih, k>=64 -> W_hh[k-64]
    // B-frag layout (16x16x32): lane = kb*16 + col; elems = 8 consecutive k
    bf16x8 wf[4][6];
    #pragma unroll
    for (int g = 0; g < 4; ++g) {
        const int n = g * 128 + w * 16 + lrow;   // gate column owned by lane
        #pragma unroll
        for (int kt = 0; kt < 6; ++kt) {
            const int k0 = kt * 32 + lkb * 8;
            const float* src = (kt < 2) ? (W_ih + n * F_ + k0)
                                        : (W_hh + n * H_ + (k0 - 64));
            bf16x8 v;
            #pragma unroll
            for (int e = 0; e < 8; ++e) v[e] = (short)f2bf(src[e]);
            wf[g][kt] = v;
        }
    }

    // bias per gate (same across the 4 C-rows a lane owns)
    float bias[4];
    #pragma unroll
    for (int g = 0; g < 4; ++g) {
        const int n = g * 128 + w * 16 + lrow;
        bias[g] = b_ih[n] + b_hh[n];
    }

    // ---------- c state in fp32 registers (matches C-tile layout) ----------
    const int hcol = w * 16 + lrow;    // hidden dim owned by this lane
    float c[4];
    #pragma unroll
    for (int q = 0; q < 4; ++q) {
        const int r = lkb * 4 + q;
        c[q] = cs0[(b0 + r) * H_ + hcol];
    }

    // ---------- stage h0 (bf16) and x_0 ----------
    {
        const int row = tid >> 5;       // 0..15
        const int c4  = (tid & 31) * 4; // 0..124
        const float4 hv = *(const float4*)(hs0 + (size_t)(b0 + row) * H_ + c4);
        *(unsigned*)&h_lds[0][row * HS + c4]     = pack2(hv.x, hv.y);
        *(unsigned*)&h_lds[0][row * HS + c4 + 2] = pack2(hv.z, hv.w);

        const int cp = tid & 31;        // 0..31 (pairs of floats)
        const float2 xv = *(const float2*)(x + (size_t)(b0 + row) * (T_ * F_) + cp * 2);
        *(unsigned*)&x_lds[0][row * XS + cp * 2] = pack2(xv.x, xv.y);
    }
    __syncthreads();

    // ---------- the T-step recurrence ----------
    for (int t = 0; t < T_; ++t) {
        // prefetch x_{t+1} (global -> regs) early; written to LDS pre-barrier
        const int prow = tid >> 5;
        const int pcp  = tid & 31;
        float2 xp;
        if (t + 1 < T_) {
            const float* p = x + (size_t)(b0 + prow) * (T_ * F_) + (t + 1) * F_ + pcp * 2;
            xp.x = p[0]; xp.y = p[1];
        }

        // A-fragments: [x_t | h_t] rows, 6 K-tiles of 32
        const unsigned short* xs = x_lds[t & 1];
        const unsigned short* hsrc = h_lds[t & 1];
        bf16x8 af[6];
        #pragma unroll
        for (int kt = 0; kt < 2; ++kt)
            af[kt] = *(const bf16x8*)&xs[lrow * XS + kt * 32 + lkb * 8];
        #pragma unroll
        for (int kt = 0; kt < 4; ++kt)
            af[2 + kt] = *(const bf16x8*)&hsrc[lrow * HS + kt * 32 + lkb * 8];

        // gates = bias + [x|h] @ W^T   (4 gate tiles, 6 K-steps each)
        f32x4 acc[4];
        #pragma unroll
        for (int g = 0; g < 4; ++g) {
            f32x4 a = {bias[g], bias[g], bias[g], bias[g]};
            acc[g] = a;
        }
        #pragma unroll
        for (int g = 0; g < 4; ++g) {
            #pragma unroll
            for (int kt = 0; kt < 6; ++kt)
                acc[g] = __builtin_amdgcn_mfma_f32_16x16x32_bf16(af[kt], wf[g][kt], acc[g], 0, 0, 0);
        }

        // LSTM cell update (fp32), rows lkb*4+q, col hcol
        unsigned short* hdst = h_lds[(t + 1) & 1];
        #pragma unroll
        for (int q = 0; q < 4; ++q) {
            const float i_ = sigmoidf_(acc[0][q]);
            const float f_ = sigmoidf_(acc[1][q]);
            const float g_ = tanhf_(acc[2][q]);
            const float o_ = sigmoidf_(acc[3][q]);
            const float cn = __fmaf_rn(f_, c[q], i_ * g_);
            c[q] = cn;
            const float hn = o_ * tanhf_(cn);
            const int r = lkb * 4 + q;
            if (t == T_ - 1) {
                h_f32[r][hcol] = hn;           // final h in fp32 for the head
            } else {
                hdst[r * HS + hcol] = f2bf(hn);
            }
        }

        // commit x_{t+1} to its LDS buffer (pre-barrier)
        if (t + 1 < T_) {
            *(unsigned*)&x_lds[(t + 1) & 1][prow * XS + pcp * 2] = pack2(xp.x, xp.y);
        }
        __syncthreads();
    }

    // ---------- head: out[b] = [h, static] @ W_lin^T + b_lin (fp32) ----------
    // wave w handles rows 2w and 2w+1
    #pragma unroll
    for (int rr = 0; rr < 2; ++rr) {
        const int r = w * 2 + rr;
        float p = h_f32[r][lane] * W_lin[lane]
                + h_f32[r][64 + lane] * W_lin[64 + lane];
        if (lane < S_) p += statik[(size_t)(b0 + r) * S_ + lane] * W_lin[128 + lane];
        #pragma unroll
        for (int m = 32; m > 0; m >>= 1) p += __shfl_xor(p, m, 64);
        if (lane == 0) out[b0 + r] = p + b_lin[0];
    }
}

extern "C" void kernel_launch(void* const* d_in, const int* in_sizes, int n_in,
                              void* d_out, int out_size, void* d_ws, size_t ws_size,
                              hipStream_t stream) {
    const float* x     = (const float*)d_in[0];
    const float* st    = (const float*)d_in[1];
    const float* hs0   = (const float*)d_in[2];
    const float* cs0   = (const float*)d_in[3];
    const float* W_ih  = (const float*)d_in[4];
    const float* W_hh  = (const float*)d_in[5];
    const float* b_ih  = (const float*)d_in[6];
    const float* b_hh  = (const float*)d_in[7];
    const float* W_lin = (const float*)d_in[8];
    const float* b_lin = (const float*)d_in[9];
    float* out = (float*)d_out;

    lstm_fused_kernel<<<dim3(B_ / 16), dim3(512), 0, stream>>>(
        x, st, hs0, cs0, W_ih, W_hh, b_ih, b_hh, W_lin, b_lin, out);
}

// Round 2
// 254.652 us; speedup vs baseline: 1.6579x; 1.6579x over previous
//
#include <hip/hip_runtime.h>
#include <hip/hip_bf16.h>

// Problem constants
#define B_ 4096
#define T_ 256
#define F_ 64
#define H_ 128
#define S_ 32

typedef __attribute__((ext_vector_type(8))) short bf16x8;
typedef __attribute__((ext_vector_type(4))) float f32x4;

// LDS row strides (bf16 elems). 72*2=144B=36 banks, 136*2=272B=68 banks;
// both ≡ 4 (mod 32) -> ~2-way aliasing on frag reads (free per m136).
#define XS 72
#define HS 136

#define K1f (-1.4426950408889634f)   // -log2(e)
#define K2f (-2.8853900817779268f)   // -2*log2(e)

__device__ __forceinline__ float bf2f(unsigned short u) {
    unsigned v = (unsigned)u << 16;
    return __builtin_bit_cast(float, v);
}
__device__ __forceinline__ short f2bs(float f) {
    return (short)__bfloat16_as_ushort(__float2bfloat16(f));
}

// One LSTM step. Reads x,h frags from XR/HR, writes h_{t+1} to HW; optionally
// stages next x tile (global->LDS XW). Ends with the step barrier.
#define LSTM_PHASE(XR, HR, HW, XW, STAGE_EN)                                      \
  {                                                                               \
    float2 xpre;                                                                  \
    const bool st_ = (STAGE_EN);                                                  \
    if (st_) xpre = *(const float2*)gxp;                                          \
    bf16x8 a[6];                                                                  \
    a[0] = *(const bf16x8*)&XR[fxb];                                              \
    a[1] = *(const bf16x8*)&XR[fxb + 32];                                         \
    a[2] = *(const bf16x8*)&HR[fhb];                                              \
    a[3] = *(const bf16x8*)&HR[fhb + 32];                                         \
    a[4] = *(const bf16x8*)&HR[fhb + 64];                                         \
    a[5] = *(const bf16x8*)&HR[fhb + 96];                                         \
    f32x4 ac[4];                                                                  \
    _Pragma("unroll")                                                             \
    for (int g = 0; g < 4; ++g)                                                   \
      ac[g] = __builtin_amdgcn_mfma_f32_16x16x32_bf16(wf[g][0], a[0], z4, 0, 0, 0); \
    _Pragma("unroll")                                                             \
    for (int kt = 1; kt < 6; ++kt) {                                              \
      _Pragma("unroll")                                                           \
      for (int g = 0; g < 4; ++g)                                                 \
        ac[g] = __builtin_amdgcn_mfma_f32_16x16x32_bf16(wf[g][kt], a[kt], ac[g], 0, 0, 0); \
    }                                                                             \
    float hn[4];                                                                  \
    _Pragma("unroll")                                                             \
    for (int q = 0; q < 4; ++q) {                                                 \
      const float ei = __builtin_amdgcn_exp2f(__builtin_fmaf(ac[0][q], K1f, bs0[q])); \
      const float i_ = __builtin_amdgcn_rcpf(1.0f + ei);                          \
      const float ef = __builtin_amdgcn_exp2f(__builtin_fmaf(ac[1][q], K1f, bs1[q])); \
      const float f_ = __builtin_amdgcn_rcpf(1.0f + ef);                          \
      const float eg = __builtin_amdgcn_exp2f(__builtin_fmaf(ac[2][q], K2f, btn[q])); \
      const float g_ = __builtin_fmaf(2.0f, __builtin_amdgcn_rcpf(1.0f + eg), -1.0f); \
      const float eo = __builtin_amdgcn_exp2f(__builtin_fmaf(ac[3][q], K1f, bs3[q])); \
      const float o_ = __builtin_amdgcn_rcpf(1.0f + eo);                          \
      const float cn = __builtin_fmaf(f_, c[q], i_ * g_);                         \
      c[q] = cn;                                                                  \
      const float ec = __builtin_amdgcn_exp2f(cn * K2f);                          \
      const float th = __builtin_fmaf(2.0f, __builtin_amdgcn_rcpf(1.0f + ec), -1.0f); \
      hn[q] = o_ * th;                                                            \
    }                                                                             \
    {                                                                             \
      float2 p0; p0.x = hn[0]; p0.y = hn[1];                                      \
      float2 p1; p1.x = hn[2]; p1.y = hn[3];                                      \
      __hip_bfloat162 b01 = __float22bfloat162_rn(p0);                            \
      __hip_bfloat162 b23 = __float22bfloat162_rn(p1);                            \
      uint2 uv; uv.x = *(unsigned*)&b01; uv.y = *(unsigned*)&b23;                 \
      *(uint2*)&HW[hwo] = uv;                                                     \
    }                                                                             \
    if (st_) {                                                                    \
      __hip_bfloat162 qx = __float22bfloat162_rn(xpre);                           \
      *(__hip_bfloat162*)&XW[xwo] = qx;                                           \
      gxp += F_;                                                                  \
    }                                                                             \
    __syncthreads();                                                              \
  }

__global__ __launch_bounds__(512, 2) void lstm_fused_kernel(
    const float* __restrict__ x,      // [B,T,F]
    const float* __restrict__ statik, // [B,S]
    const float* __restrict__ hs0,    // [B,H]
    const float* __restrict__ cs0,    // [B,H]
    const float* __restrict__ W_ih,   // [4H,F]
    const float* __restrict__ W_hh,   // [4H,H]
    const float* __restrict__ b_ih,   // [4H]
    const float* __restrict__ b_hh,   // [4H]
    const float* __restrict__ W_lin,  // [H+S]
    const float* __restrict__ b_lin,  // [1]
    float* __restrict__ out)          // [B]
{
    __shared__ unsigned short x_l[2][16 * XS];
    __shared__ unsigned short h_l[2][16 * HS];

    const int tid  = threadIdx.x;
    const int lane = tid & 63;
    const int w    = tid >> 6;         // wave 0..7
    const int b0   = blockIdx.x * 16;

    const int lrow = lane & 15;        // batch row (B-frag col / C col)
    const int lkb  = lane >> 4;        // k-group / C row-group
    const int n0q  = w * 16 + lkb * 4; // hidden-dim base owned by this lane

    // ---- one-time: weight fragments (A-operand) into registers, bf16 ----
    // lane holds W[n = g*128 + w*16 + lrow][k = kt*32 + lkb*8 + e]
    bf16x8 wf[4][6];
    #pragma unroll
    for (int g = 0; g < 4; ++g) {
        const int n = g * 128 + w * 16 + lrow;
        #pragma unroll
        for (int kt = 0; kt < 6; ++kt) {
            const int k0 = kt * 32 + lkb * 8;
            const float* src = (kt < 2) ? (W_ih + n * F_ + k0)
                                        : (W_hh + n * H_ + (k0 - 64));
            const float4 s0 = *(const float4*)(src);
            const float4 s1 = *(const float4*)(src + 4);
            bf16x8 v;
            v[0] = f2bs(s0.x); v[1] = f2bs(s0.y); v[2] = f2bs(s0.z); v[3] = f2bs(s0.w);
            v[4] = f2bs(s1.x); v[5] = f2bs(s1.y); v[6] = f2bs(s1.z); v[7] = f2bs(s1.w);
            wf[g][kt] = v;
        }
    }

    // ---- biases, pre-scaled into the exp2 argument ----
    float bs0[4], bs1[4], btn[4], bs3[4];
    #pragma unroll
    for (int g = 0; g < 4; ++g) {
        const float4 bi = *(const float4*)(b_ih + g * 128 + n0q);
        const float4 bh = *(const float4*)(b_hh + g * 128 + n0q);
        const float bq[4] = {bi.x + bh.x, bi.y + bh.y, bi.z + bh.z, bi.w + bh.w};
        #pragma unroll
        for (int q = 0; q < 4; ++q) {
            if (g == 0)      bs0[q] = bq[q] * K1f;
            else if (g == 1) bs1[q] = bq[q] * K1f;
            else if (g == 2) btn[q] = bq[q] * K2f;
            else             bs3[q] = bq[q] * K1f;
        }
    }

    // ---- c state: lane owns c[batch=lrow][n0q .. n0q+3] (contiguous!) ----
    float c[4];
    {
        const float4 cv = *(const float4*)(cs0 + (size_t)(b0 + lrow) * H_ + n0q);
        c[0] = cv.x; c[1] = cv.y; c[2] = cv.z; c[3] = cv.w;
    }

    // ---- prologue staging: h0 and x_0 (fp32 -> bf16 LDS) ----
    const int srow = tid >> 5;      // 0..15
    const int scp  = tid & 31;      // pair index 0..31
    {
        const float* hp = hs0 + (size_t)(b0 + srow) * H_ + scp * 2;
        const float2 hv0 = *(const float2*)(hp);
        const float2 hv1 = *(const float2*)(hp + 64);
        __hip_bfloat162 q0 = __float22bfloat162_rn(hv0);
        __hip_bfloat162 q1 = __float22bfloat162_rn(hv1);
        *(__hip_bfloat162*)&h_l[0][srow * HS + scp * 2]      = q0;
        *(__hip_bfloat162*)&h_l[0][srow * HS + 64 + scp * 2] = q1;
    }
    const float* gxp = x + (size_t)(b0 + srow) * (T_ * F_) + scp * 2;
    {
        const float2 xv = *(const float2*)gxp;
        __hip_bfloat162 qx = __float22bfloat162_rn(xv);
        *(__hip_bfloat162*)&x_l[0][srow * XS + scp * 2] = qx;
    }
    gxp += F_;
    __syncthreads();

    // ---- step-invariant offsets (elements) ----
    const int fxb = lrow * XS + lkb * 8;
    const int fhb = lrow * HS + lkb * 8;
    const int hwo = lrow * HS + n0q;       // h write: 4 consecutive bf16 = b64
    const int xwo = srow * XS + scp * 2;
    const f32x4 z4 = {0.0f, 0.0f, 0.0f, 0.0f};

    // ---- recurrence: 2 steps per iteration, compile-time ping-pong ----
    for (int t = 0; t < T_; t += 2) {
        LSTM_PHASE(x_l[0], h_l[0], h_l[1], x_l[1], true);
        LSTM_PHASE(x_l[1], h_l[1], h_l[0], x_l[0], (t + 2 < T_));
    }

    // ---- head: out[b] = [h,static]@W_lin^T + b (h read as bf16) ----
    {
        const unsigned short* hf = h_l[0];
        const float wl0 = W_lin[lane];
        const float wl1 = W_lin[64 + lane];
        const float wl2 = (lane < S_) ? W_lin[128 + lane] : 0.0f;
        const float bl  = b_lin[0];
        #pragma unroll
        for (int rr = 0; rr < 2; ++rr) {
            const int r = w * 2 + rr;
            float p = bf2f(hf[r * HS + lane]) * wl0
                    + bf2f(hf[r * HS + 64 + lane]) * wl1;
            if (lane < S_) p += statik[(size_t)(b0 + r) * S_ + lane] * wl2;
            #pragma unroll
            for (int m = 32; m > 0; m >>= 1) p += __shfl_xor(p, m, 64);
            if (lane == 0) out[b0 + r] = p + bl;
        }
    }
}

extern "C" void kernel_launch(void* const* d_in, const int* in_sizes, int n_in,
                              void* d_out, int out_size, void* d_ws, size_t ws_size,
                              hipStream_t stream) {
    const float* x     = (const float*)d_in[0];
    const float* st    = (const float*)d_in[1];
    const float* hs0   = (const float*)d_in[2];
    const float* cs0   = (const float*)d_in[3];
    const float* W_ih  = (const float*)d_in[4];
    const float* W_hh  = (const float*)d_in[5];
    const float* b_ih  = (const float*)d_in[6];
    const float* b_hh  = (const float*)d_in[7];
    const float* W_lin = (const float*)d_in[8];
    const float* b_lin = (const float*)d_in[9];
    float* out = (float*)d_out;

    lstm_fused_kernel<<<dim3(B_ / 16), dim3(512), 0, stream>>>(
        x, st, hs0, cs0, W_ih, W_hh, b_ih, b_hh, W_lin, b_lin, out);
}